// Round 1
// baseline (5876.817 us; speedup 1.0000x reference)
//
#include <hip/hip_runtime.h>
#include <math.h>

#define DIM 1024
#define HEADS 16
#define HEAD_DIM 64
#define HIDDEN 4096
#define NSEQ 1024
#define BATCH 4
#define TOKENS (BATCH * NSEQ)
#define EPS 1e-5f

// ---------------- LayerNorm: one block (256 thr) per token ----------------
__global__ __launch_bounds__(256) void ln_kernel(const float* __restrict__ x,
                                                 const float* __restrict__ g,
                                                 const float* __restrict__ b,
                                                 float* __restrict__ out) {
    const int t = blockIdx.x;
    const int tid = threadIdx.x;
    const float* row = x + (size_t)t * DIM;
    float v[4];
    float s1 = 0.f, s2 = 0.f;
#pragma unroll
    for (int i = 0; i < 4; i++) {
        v[i] = row[tid + i * 256];
        s1 += v[i];
        s2 += v[i] * v[i];
    }
    // wave(64) shuffle reduce, then LDS across 4 waves
    __shared__ float w1[4], w2[4];
#pragma unroll
    for (int off = 32; off > 0; off >>= 1) {
        s1 += __shfl_down(s1, off, 64);
        s2 += __shfl_down(s2, off, 64);
    }
    const int wave = tid >> 6;
    if ((tid & 63) == 0) { w1[wave] = s1; w2[wave] = s2; }
    __syncthreads();
    const float sum = w1[0] + w1[1] + w1[2] + w1[3];
    const float ssq = w2[0] + w2[1] + w2[2] + w2[3];
    const float mu = sum * (1.0f / DIM);
    const float var = ssq * (1.0f / DIM) - mu * mu;
    const float rstd = rsqrtf(var + EPS);
    float* orow = out + (size_t)t * DIM;
#pragma unroll
    for (int i = 0; i < 4; i++) {
        const int idx = tid + i * 256;
        orow[idx] = (v[i] - mu) * rstd * g[idx] + b[idx];
    }
}

// ---------------- Generic GEMM: C[M,N] = A[M,K] @ W[N,K]^T + bias (+gelu) (+res)
// 64x64 tile, K-step 16, 256 threads, 4x4 micro-tile.
#define ACT_NONE 0
#define ACT_GELU 1

template <int ACT, bool RES>
__global__ __launch_bounds__(256) void gemm_kernel(const float* __restrict__ A,
                                                   const float* __restrict__ W,
                                                   const float* __restrict__ bias,
                                                   const float* __restrict__ res,
                                                   float* __restrict__ C,
                                                   int M, int N, int K) {
    __shared__ float As[16][68];
    __shared__ float Ws[16][68];
    const int bm = blockIdx.y * 64;
    const int bn = blockIdx.x * 64;
    const int tid = threadIdx.x;
    const int r = tid >> 2;        // 0..63: tile row to load
    const int c4 = tid & 3;        // which float4 along K
    const int m0 = (tid & 15) * 4;
    const int n0 = (tid >> 4) * 4;

    float acc[4][4] = {};

    for (int kk = 0; kk < K; kk += 16) {
        float4 a4 = *(const float4*)(A + (size_t)(bm + r) * K + kk + c4 * 4);
        float4 w4 = *(const float4*)(W + (size_t)(bn + r) * K + kk + c4 * 4);
        As[c4 * 4 + 0][r] = a4.x; As[c4 * 4 + 1][r] = a4.y;
        As[c4 * 4 + 2][r] = a4.z; As[c4 * 4 + 3][r] = a4.w;
        Ws[c4 * 4 + 0][r] = w4.x; Ws[c4 * 4 + 1][r] = w4.y;
        Ws[c4 * 4 + 2][r] = w4.z; Ws[c4 * 4 + 3][r] = w4.w;
        __syncthreads();
#pragma unroll
        for (int k = 0; k < 16; k++) {
            const float4 av = *(const float4*)&As[k][m0];
            const float4 wv = *(const float4*)&Ws[k][n0];
            const float a[4] = {av.x, av.y, av.z, av.w};
            const float w[4] = {wv.x, wv.y, wv.z, wv.w};
#pragma unroll
            for (int i = 0; i < 4; i++)
#pragma unroll
                for (int j = 0; j < 4; j++) acc[i][j] += a[i] * w[j];
        }
        __syncthreads();
    }

#pragma unroll
    for (int i = 0; i < 4; i++) {
        const size_t m = bm + m0 + i;
#pragma unroll
        for (int j = 0; j < 4; j++) {
            const int n = bn + n0 + j;
            float val = acc[i][j] + bias[n];
            if (ACT == ACT_GELU) val = 0.5f * val * (1.0f + erff(val * 0.70710678118654752f));
            if (RES) val += res[m * N + n];
            C[m * N + n] = val;
        }
    }
}

// ---------------- Attention: one block (256 thr) per (b, h, q) ----------------
// qkv layout: [token, 3*DIM], cols 0..1023=q, 1024..2047=k, 2048..3071=v; head h owns cols h*64..h*64+63
__global__ __launch_bounds__(256) void attn_kernel(const float* __restrict__ qkv,
                                                   float* __restrict__ out) {
    __shared__ float q_s[HEAD_DIM];
    __shared__ float sc[NSEQ];
    __shared__ float red[4 * HEAD_DIM];
    __shared__ float wred[8];

    const int bid = blockIdx.x;
    const int qi = bid & (NSEQ - 1);
    const int h = (bid >> 10) & (HEADS - 1);
    const int b = bid >> 14;
    const int tid = threadIdx.x;

    const size_t tq = (size_t)b * NSEQ + qi;
    const float* qptr = qkv + tq * (3 * DIM) + h * HEAD_DIM;
    const float* kbase = qkv + (size_t)b * NSEQ * (3 * DIM) + DIM + h * HEAD_DIM;
    const float* vbase = kbase + DIM;

    if (tid < HEAD_DIM) q_s[tid] = qptr[tid] * 0.125f;  // scale = HEAD_DIM^-0.5
    __syncthreads();

    float svals[4];
    float lmax = -INFINITY;
#pragma unroll
    for (int j = 0; j < 4; j++) {
        const int m = tid + j * 256;
        const float4* kr = (const float4*)(kbase + (size_t)m * (3 * DIM));
        float dot = 0.f;
#pragma unroll
        for (int kkk = 0; kkk < 16; kkk++) {
            const float4 kv = kr[kkk];
            dot += q_s[kkk * 4 + 0] * kv.x + q_s[kkk * 4 + 1] * kv.y +
                   q_s[kkk * 4 + 2] * kv.z + q_s[kkk * 4 + 3] * kv.w;
        }
        svals[j] = dot;
        lmax = fmaxf(lmax, dot);
    }
#pragma unroll
    for (int off = 32; off > 0; off >>= 1) lmax = fmaxf(lmax, __shfl_down(lmax, off, 64));
    const int wave = tid >> 6;
    if ((tid & 63) == 0) wred[wave] = lmax;
    __syncthreads();
    const float mx = fmaxf(fmaxf(wred[0], wred[1]), fmaxf(wred[2], wred[3]));

    float lsum = 0.f;
#pragma unroll
    for (int j = 0; j < 4; j++) {
        const int m = tid + j * 256;
        const float e = __expf(svals[j] - mx);
        sc[m] = e;
        lsum += e;
    }
#pragma unroll
    for (int off = 32; off > 0; off >>= 1) lsum += __shfl_down(lsum, off, 64);
    if ((tid & 63) == 0) wred[4 + wave] = lsum;
    __syncthreads();
    const float inv = 1.0f / (wred[4] + wred[5] + wred[6] + wred[7]);

    // o[d] = sum_m p[m] * v[m,d]; thread t handles d = t&63 over keys chunk c = t>>6
    const int d = tid & 63;
    const int c = tid >> 6;
    float part = 0.f;
    const float* vp = vbase + d;
    for (int m = c * 256; m < c * 256 + 256; m++) part += sc[m] * vp[(size_t)m * (3 * DIM)];
    red[c * 64 + d] = part;
    __syncthreads();
    if (c == 0) {
        const float tot = red[d] + red[64 + d] + red[128 + d] + red[192 + d];
        out[tq * DIM + h * HEAD_DIM + d] = tot * inv;
    }
}

// ---------------- launch ----------------
extern "C" void kernel_launch(void* const* d_in, const int* in_sizes, int n_in,
                              void* d_out, int out_size, void* d_ws, size_t ws_size,
                              hipStream_t stream) {
    const float* x      = (const float*)d_in[0];
    const float* ln1_g  = (const float*)d_in[1];
    const float* ln1_b  = (const float*)d_in[2];
    const float* qkv_w  = (const float*)d_in[3];
    const float* qkv_b  = (const float*)d_in[4];
    const float* proj_w = (const float*)d_in[5];
    const float* proj_b = (const float*)d_in[6];
    const float* ln2_g  = (const float*)d_in[7];
    const float* ln2_b  = (const float*)d_in[8];
    const float* fc1_w  = (const float*)d_in[9];
    const float* fc1_b  = (const float*)d_in[10];
    const float* fc2_w  = (const float*)d_in[11];
    const float* fc2_b  = (const float*)d_in[12];
    float* out = (float*)d_out;

    float* h_buf    = (float*)d_ws;                        // [TOKENS, DIM]
    float* qkv_buf  = h_buf + (size_t)TOKENS * DIM;        // [TOKENS, 3*DIM]
    float* attn_buf = qkv_buf + (size_t)TOKENS * 3 * DIM;  // [TOKENS, DIM]
    float* ffn_buf  = attn_buf + (size_t)TOKENS * DIM;     // [TOKENS, HIDDEN]

    // 1) h = LN1(x)
    ln_kernel<<<TOKENS, 256, 0, stream>>>(x, ln1_g, ln1_b, h_buf);
    // 2) qkv = h @ qkv_w^T + qkv_b
    gemm_kernel<ACT_NONE, false><<<dim3(3 * DIM / 64, TOKENS / 64), 256, 0, stream>>>(
        h_buf, qkv_w, qkv_b, nullptr, qkv_buf, TOKENS, 3 * DIM, DIM);
    // 3) attention
    attn_kernel<<<BATCH * HEADS * NSEQ, 256, 0, stream>>>(qkv_buf, attn_buf);
    // 4) x1 = x + attn @ proj_w^T + proj_b   -> d_out
    gemm_kernel<ACT_NONE, true><<<dim3(DIM / 64, TOKENS / 64), 256, 0, stream>>>(
        attn_buf, proj_w, proj_b, x, out, TOKENS, DIM, DIM);
    // 5) h2 = LN2(x1)  (reuse h_buf)
    ln_kernel<<<TOKENS, 256, 0, stream>>>(out, ln2_g, ln2_b, h_buf);
    // 6) ffn = gelu(h2 @ fc1_w^T + fc1_b)
    gemm_kernel<ACT_GELU, false><<<dim3(HIDDEN / 64, TOKENS / 64), 256, 0, stream>>>(
        h_buf, fc1_w, fc1_b, nullptr, ffn_buf, TOKENS, HIDDEN, DIM);
    // 7) out = x1 + ffn @ fc2_w^T + fc2_b  (in-place residual on d_out)
    gemm_kernel<ACT_NONE, true><<<dim3(DIM / 64, TOKENS / 64), 256, 0, stream>>>(
        ffn_buf, fc2_w, fc2_b, out, out, TOKENS, DIM, HIDDEN);
}

// Round 2
// 1789.277 us; speedup vs baseline: 3.2845x; 3.2845x over previous
//
#include <hip/hip_runtime.h>
#include <math.h>

#define DIM 1024
#define HEADS 16
#define HEAD_DIM 64
#define HIDDEN 4096
#define NSEQ 1024
#define BATCH 4
#define TOKENS (BATCH * NSEQ)
#define EPS 1e-5f

// ---------------- LayerNorm: one block (256 thr) per token ----------------
__global__ __launch_bounds__(256) void ln_kernel(const float* __restrict__ x,
                                                 const float* __restrict__ g,
                                                 const float* __restrict__ b,
                                                 float* __restrict__ out) {
    const int t = blockIdx.x;
    const int tid = threadIdx.x;
    const float* row = x + (size_t)t * DIM;
    float v[4];
    float s1 = 0.f, s2 = 0.f;
#pragma unroll
    for (int i = 0; i < 4; i++) {
        v[i] = row[tid + i * 256];
        s1 += v[i];
        s2 += v[i] * v[i];
    }
    __shared__ float w1[4], w2[4];
#pragma unroll
    for (int off = 32; off > 0; off >>= 1) {
        s1 += __shfl_down(s1, off, 64);
        s2 += __shfl_down(s2, off, 64);
    }
    const int wave = tid >> 6;
    if ((tid & 63) == 0) { w1[wave] = s1; w2[wave] = s2; }
    __syncthreads();
    const float sum = w1[0] + w1[1] + w1[2] + w1[3];
    const float ssq = w2[0] + w2[1] + w2[2] + w2[3];
    const float mu = sum * (1.0f / DIM);
    const float var = ssq * (1.0f / DIM) - mu * mu;
    const float rstd = rsqrtf(var + EPS);
    float* orow = out + (size_t)t * DIM;
#pragma unroll
    for (int i = 0; i < 4; i++) {
        const int idx = tid + i * 256;
        orow[idx] = (v[i] - mu) * rstd * g[idx] + b[idx];
    }
}

// ---------------- Generic GEMM: C[M,N] = A[M,K] @ W[N,K]^T + bias (+gelu) (+res)
#define ACT_NONE 0
#define ACT_GELU 1

template <int ACT, bool RES>
__global__ __launch_bounds__(256) void gemm_kernel(const float* __restrict__ A,
                                                   const float* __restrict__ W,
                                                   const float* __restrict__ bias,
                                                   const float* __restrict__ res,
                                                   float* __restrict__ C,
                                                   int M, int N, int K) {
    __shared__ float As[16][68];
    __shared__ float Ws[16][68];
    const int bm = blockIdx.y * 64;
    const int bn = blockIdx.x * 64;
    const int tid = threadIdx.x;
    const int r = tid >> 2;
    const int c4 = tid & 3;
    const int m0 = (tid & 15) * 4;
    const int n0 = (tid >> 4) * 4;

    float acc[4][4] = {};

    for (int kk = 0; kk < K; kk += 16) {
        float4 a4 = *(const float4*)(A + (size_t)(bm + r) * K + kk + c4 * 4);
        float4 w4 = *(const float4*)(W + (size_t)(bn + r) * K + kk + c4 * 4);
        As[c4 * 4 + 0][r] = a4.x; As[c4 * 4 + 1][r] = a4.y;
        As[c4 * 4 + 2][r] = a4.z; As[c4 * 4 + 3][r] = a4.w;
        Ws[c4 * 4 + 0][r] = w4.x; Ws[c4 * 4 + 1][r] = w4.y;
        Ws[c4 * 4 + 2][r] = w4.z; Ws[c4 * 4 + 3][r] = w4.w;
        __syncthreads();
#pragma unroll
        for (int k = 0; k < 16; k++) {
            const float4 av = *(const float4*)&As[k][m0];
            const float4 wv = *(const float4*)&Ws[k][n0];
            const float a[4] = {av.x, av.y, av.z, av.w};
            const float w[4] = {wv.x, wv.y, wv.z, wv.w};
#pragma unroll
            for (int i = 0; i < 4; i++)
#pragma unroll
                for (int j = 0; j < 4; j++) acc[i][j] += a[i] * w[j];
        }
        __syncthreads();
    }

#pragma unroll
    for (int i = 0; i < 4; i++) {
        const size_t m = bm + m0 + i;
#pragma unroll
        for (int j = 0; j < 4; j++) {
            const int n = bn + n0 + j;
            float val = acc[i][j] + bias[n];
            if (ACT == ACT_GELU) val = 0.5f * val * (1.0f + erff(val * 0.70710678118654752f));
            if (RES) val += res[m * N + n];
            C[m * N + n] = val;
        }
    }
}

// ---------------- Flash attention: one block (256 thr) per (b, h, 64-query tile)
// qkv layout: [token, 3*DIM]; head h owns cols h*64..h*64+63 of each of q/k/v thirds.
// LDS: Qs/Ks in [d][row] layout (transposed), Vs in [key][d], Ps (=S then P) in [key][qrow].
__global__ __launch_bounds__(256) void fattn_kernel(const float* __restrict__ qkv,
                                                    float* __restrict__ out) {
    __shared__ float Qs[64][68];   // [d][i]
    __shared__ float Ks[64][68];   // [d][j]
    __shared__ float Vs[64][68];   // [j][d]
    __shared__ float Ps[64][68];   // [j][i]
    __shared__ float red[4][64];
    __shared__ float mrow[64], lrow[64], alph[64];

    const int bid = blockIdx.x;          // b*256 + h*16 + qt
    const int qt = bid & 15;
    const int h = (bid >> 4) & 15;
    const int b = bid >> 8;
    const int tid = threadIdx.x;
    const int ti = tid & 15, tj = tid >> 4;
    const int i0 = ti * 4, d0 = tj * 4;  // thread's 4 q-rows, 4 cols (keys for S, dims for O)

    const size_t base = (size_t)b * NSEQ * (3 * DIM);
    const float* qb = qkv + base + h * HEAD_DIM;
    const float* kb = qkv + base + DIM + h * HEAD_DIM;
    const float* vb = qkv + base + 2 * DIM + h * HEAD_DIM;

    // Q tile -> LDS transposed [d][i], pre-scaled by 1/sqrt(64)
    {
        const int i = tid >> 2, c = tid & 3;
        const float* src = qb + (size_t)(qt * 64 + i) * (3 * DIM) + c * 4;
#pragma unroll
        for (int f = 0; f < 4; f++) {
            float4 v4 = *(const float4*)(src + f * 16);
            const int d = f * 16 + c * 4;
            Qs[d + 0][i] = v4.x * 0.125f;
            Qs[d + 1][i] = v4.y * 0.125f;
            Qs[d + 2][i] = v4.z * 0.125f;
            Qs[d + 3][i] = v4.w * 0.125f;
        }
    }
    if (tid < 64) { mrow[tid] = -INFINITY; lrow[tid] = 0.f; }

    float o[4][4] = {};

    for (int k0 = 0; k0 < NSEQ; k0 += 64) {
        __syncthreads();  // previous iteration's readers of Ks/Vs/Ps are done
        {
            const int j = tid >> 2, c = tid & 3;
            const float* ks = kb + (size_t)(k0 + j) * (3 * DIM) + c * 4;
            const float* vs = vb + (size_t)(k0 + j) * (3 * DIM) + c * 4;
#pragma unroll
            for (int f = 0; f < 4; f++) {
                float4 v4 = *(const float4*)(ks + f * 16);
                const int d = f * 16 + c * 4;
                Ks[d + 0][j] = v4.x; Ks[d + 1][j] = v4.y;
                Ks[d + 2][j] = v4.z; Ks[d + 3][j] = v4.w;
            }
#pragma unroll
            for (int f = 0; f < 4; f++) {
                *(float4*)&Vs[j][f * 16 + c * 4] = *(const float4*)(vs + f * 16);
            }
        }
        __syncthreads();

        // S[i][j] = sum_d Qs[d][i] * Ks[d][j]  (4x4 per thread)
        float s[4][4] = {};
#pragma unroll 8
        for (int d = 0; d < 64; d++) {
            const float4 a = *(const float4*)&Qs[d][i0];
            const float4 w = *(const float4*)&Ks[d][d0];
            const float aa[4] = {a.x, a.y, a.z, a.w};
            const float ww[4] = {w.x, w.y, w.z, w.w};
#pragma unroll
            for (int ii = 0; ii < 4; ii++)
#pragma unroll
                for (int jj = 0; jj < 4; jj++) s[ii][jj] += aa[ii] * ww[jj];
        }
#pragma unroll
        for (int jj = 0; jj < 4; jj++)
            *(float4*)&Ps[d0 + jj][i0] = make_float4(s[0][jj], s[1][jj], s[2][jj], s[3][jj]);
        __syncthreads();

        // rowwise partial max (4 chunks of 16 keys per q-row)
        {
            const int r = tid & 63, c = tid >> 6;
            float pm = -INFINITY;
#pragma unroll
            for (int j = c * 16; j < c * 16 + 16; j++) pm = fmaxf(pm, Ps[j][r]);
            red[c][r] = pm;
        }
        __syncthreads();
        if (tid < 64) {
            const float mo = mrow[tid];
            float mn = fmaxf(fmaxf(red[0][tid], red[1][tid]), fmaxf(red[2][tid], red[3][tid]));
            mn = fmaxf(mn, mo);
            alph[tid] = __expf(mo - mn);   // exp(-inf - finite) = 0 on first tile
            mrow[tid] = mn;
        }
        __syncthreads();
        // P = exp(S - m), partial row sums
        {
            const int r = tid & 63, c = tid >> 6;
            const float m = mrow[r];
            float ps = 0.f;
#pragma unroll
            for (int j = c * 16; j < c * 16 + 16; j++) {
                const float p = __expf(Ps[j][r] - m);
                Ps[j][r] = p;
                ps += p;
            }
            red[c][r] = ps;
        }
        __syncthreads();
        if (tid < 64)
            lrow[tid] = lrow[tid] * alph[tid] + red[0][tid] + red[1][tid] + red[2][tid] + red[3][tid];

        // O = O*alpha + P @ V  (4x4 per thread)
        float al[4];
#pragma unroll
        for (int ii = 0; ii < 4; ii++) al[ii] = alph[i0 + ii];
#pragma unroll
        for (int ii = 0; ii < 4; ii++)
#pragma unroll
            for (int jj = 0; jj < 4; jj++) o[ii][jj] *= al[ii];
#pragma unroll 8
        for (int j = 0; j < 64; j++) {
            const float4 p4 = *(const float4*)&Ps[j][i0];
            const float4 v4 = *(const float4*)&Vs[j][d0];
            const float pp[4] = {p4.x, p4.y, p4.z, p4.w};
            const float vv[4] = {v4.x, v4.y, v4.z, v4.w};
#pragma unroll
            for (int ii = 0; ii < 4; ii++)
#pragma unroll
                for (int jj = 0; jj < 4; jj++) o[ii][jj] += pp[ii] * vv[jj];
        }
    }
    __syncthreads();

    {
        float linv[4];
#pragma unroll
        for (int ii = 0; ii < 4; ii++) linv[ii] = 1.0f / lrow[i0 + ii];
        const size_t tq0 = (size_t)b * NSEQ + qt * 64;
#pragma unroll
        for (int ii = 0; ii < 4; ii++) {
            float4 r4 = make_float4(o[ii][0] * linv[ii], o[ii][1] * linv[ii],
                                    o[ii][2] * linv[ii], o[ii][3] * linv[ii]);
            *(float4*)&out[(tq0 + i0 + ii) * DIM + h * HEAD_DIM + d0] = r4;
        }
    }
}

// ---------------- launch ----------------
extern "C" void kernel_launch(void* const* d_in, const int* in_sizes, int n_in,
                              void* d_out, int out_size, void* d_ws, size_t ws_size,
                              hipStream_t stream) {
    const float* x      = (const float*)d_in[0];
    const float* ln1_g  = (const float*)d_in[1];
    const float* ln1_b  = (const float*)d_in[2];
    const float* qkv_w  = (const float*)d_in[3];
    const float* qkv_b  = (const float*)d_in[4];
    const float* proj_w = (const float*)d_in[5];
    const float* proj_b = (const float*)d_in[6];
    const float* ln2_g  = (const float*)d_in[7];
    const float* ln2_b  = (const float*)d_in[8];
    const float* fc1_w  = (const float*)d_in[9];
    const float* fc1_b  = (const float*)d_in[10];
    const float* fc2_w  = (const float*)d_in[11];
    const float* fc2_b  = (const float*)d_in[12];
    float* out = (float*)d_out;

    float* h_buf    = (float*)d_ws;
    float* qkv_buf  = h_buf + (size_t)TOKENS * DIM;
    float* attn_buf = qkv_buf + (size_t)TOKENS * 3 * DIM;
    float* ffn_buf  = attn_buf + (size_t)TOKENS * DIM;

    ln_kernel<<<TOKENS, 256, 0, stream>>>(x, ln1_g, ln1_b, h_buf);
    gemm_kernel<ACT_NONE, false><<<dim3(3 * DIM / 64, TOKENS / 64), 256, 0, stream>>>(
        h_buf, qkv_w, qkv_b, nullptr, qkv_buf, TOKENS, 3 * DIM, DIM);
    fattn_kernel<<<BATCH * HEADS * (NSEQ / 64), 256, 0, stream>>>(qkv_buf, attn_buf);
    gemm_kernel<ACT_NONE, true><<<dim3(DIM / 64, TOKENS / 64), 256, 0, stream>>>(
        attn_buf, proj_w, proj_b, x, out, TOKENS, DIM, DIM);
    ln_kernel<<<TOKENS, 256, 0, stream>>>(out, ln2_g, ln2_b, h_buf);
    gemm_kernel<ACT_GELU, false><<<dim3(HIDDEN / 64, TOKENS / 64), 256, 0, stream>>>(
        h_buf, fc1_w, fc1_b, nullptr, ffn_buf, TOKENS, HIDDEN, DIM);
    gemm_kernel<ACT_NONE, true><<<dim3(DIM / 64, TOKENS / 64), 256, 0, stream>>>(
        ffn_buf, fc2_w, fc2_b, out, out, TOKENS, DIM, HIDDEN);
}

// Round 3
// 613.041 us; speedup vs baseline: 9.5863x; 2.9187x over previous
//
#include <hip/hip_runtime.h>
#include <math.h>

#define DIM 1024
#define HEADS 16
#define HEAD_DIM 64
#define HIDDEN 4096
#define NSEQ 1024
#define BATCH 4
#define TOKENS (BATCH * NSEQ)
#define EPS 1e-5f

typedef __bf16 bf16;
typedef __bf16 bf16x4 __attribute__((ext_vector_type(4)));
typedef __bf16 bf16x8 __attribute__((ext_vector_type(8)));
typedef float f32x4 __attribute__((ext_vector_type(4)));

#define AS1 __attribute__((address_space(1)))
#define AS3 __attribute__((address_space(3)))

// ---------------- fp32 -> bf16 weight convert ----------------
__global__ __launch_bounds__(256) void cvt_kernel(const float* __restrict__ s,
                                                  bf16* __restrict__ d) {
    const int i = (blockIdx.x * 256 + threadIdx.x) * 4;
    const float4 v = *(const float4*)(s + i);
    bf16x4 o = {(bf16)v.x, (bf16)v.y, (bf16)v.z, (bf16)v.w};
    *(bf16x4*)(d + i) = o;
}

// ---------------- LayerNorm: one block (256 thr) per token, bf16 out ----------------
__global__ __launch_bounds__(256) void ln_kernel(const float* __restrict__ x,
                                                 const float* __restrict__ g,
                                                 const float* __restrict__ b,
                                                 bf16* __restrict__ out) {
    const int t = blockIdx.x;
    const int tid = threadIdx.x;
    const float* row = x + (size_t)t * DIM;
    float v[4];
    float s1 = 0.f, s2 = 0.f;
#pragma unroll
    for (int i = 0; i < 4; i++) {
        v[i] = row[tid + i * 256];
        s1 += v[i];
        s2 += v[i] * v[i];
    }
    __shared__ float w1[4], w2[4];
#pragma unroll
    for (int off = 32; off > 0; off >>= 1) {
        s1 += __shfl_down(s1, off, 64);
        s2 += __shfl_down(s2, off, 64);
    }
    const int wave = tid >> 6;
    if ((tid & 63) == 0) { w1[wave] = s1; w2[wave] = s2; }
    __syncthreads();
    const float sum = w1[0] + w1[1] + w1[2] + w1[3];
    const float ssq = w2[0] + w2[1] + w2[2] + w2[3];
    const float mu = sum * (1.0f / DIM);
    const float var = ssq * (1.0f / DIM) - mu * mu;
    const float rstd = rsqrtf(var + EPS);
    bf16* orow = out + (size_t)t * DIM;
#pragma unroll
    for (int i = 0; i < 4; i++) {
        const int idx = tid + i * 256;
        orow[idx] = (bf16)((v[i] - mu) * rstd * g[idx] + b[idx]);
    }
}

// ---------------- bf16 MFMA GEMM (m97 structure) ----------------
// C[M,N] = A[M,K] @ W[N,K]^T + bias (+gelu) (+res). 128x128 tile, BK=32,
// 256 thr = 4 waves, each wave a 64x64 quadrant (4x4 MFMA tiles of 16x16x32).
#define ACT_NONE 0
#define ACT_GELU 1

template <int ACT, bool RES, bool OUT_BF16>
__global__ __launch_bounds__(256) void mfma_gemm(const bf16* __restrict__ A,
                                                 const bf16* __restrict__ W,
                                                 const float* __restrict__ bias,
                                                 const float* __restrict__ res,
                                                 void* __restrict__ Cout,
                                                 int M, int N, int K) {
    __shared__ __align__(16) bf16 As[128 * 32];
    __shared__ __align__(16) bf16 Bs[128 * 32];

    const int tid = threadIdx.x;
    const int w = tid >> 6, lane = tid & 63;
    const int bm = blockIdx.y * 128, bn = blockIdx.x * 128;

    // staging: thread tid covers LDS bytes [tid*16, tid*16+16) per 4KB shot.
    // LDS layout row-major [128][32] bf16: row = s*64 + tid/4, 16B chunk = tid%4.
    const bf16* pa = A + (size_t)(bm + (tid >> 2)) * K + (tid & 3) * 8;
    const bf16* pb = W + (size_t)(bn + (tid >> 2)) * K + (tid & 3) * 8;
    const size_t rowskip = (size_t)64 * K;
    char* ldsA = (char*)As + (w << 10);   // wave-uniform base; HW adds lane*16
    char* ldsB = (char*)Bs + (w << 10);

    const int wm = (w & 1) * 64, wn = (w >> 1) * 64;
    const int fm = lane & 15, fk = (lane >> 4) * 8;
    const bf16* aoff = As + (wm + fm) * 32 + fk;
    const bf16* boff = Bs + (wn + fm) * 32 + fk;

    f32x4 acc[4][4] = {};

    for (int kk = 0; kk < K; kk += 32) {
        __builtin_amdgcn_global_load_lds((const AS1 void*)pa, (AS3 void*)ldsA, 16, 0, 0);
        __builtin_amdgcn_global_load_lds((const AS1 void*)(pa + rowskip), (AS3 void*)(ldsA + 4096), 16, 0, 0);
        __builtin_amdgcn_global_load_lds((const AS1 void*)pb, (AS3 void*)ldsB, 16, 0, 0);
        __builtin_amdgcn_global_load_lds((const AS1 void*)(pb + rowskip), (AS3 void*)(ldsB + 4096), 16, 0, 0);
        pa += 32; pb += 32;
        __syncthreads();   // drains vmcnt(0) then barrier

        bf16x8 af[4], bfr[4];
#pragma unroll
        for (int t = 0; t < 4; t++) af[t] = *(const bf16x8*)(aoff + t * 16 * 32);
#pragma unroll
        for (int t = 0; t < 4; t++) bfr[t] = *(const bf16x8*)(boff + t * 16 * 32);
#pragma unroll
        for (int mt = 0; mt < 4; mt++)
#pragma unroll
            for (int nt = 0; nt < 4; nt++)
                acc[mt][nt] = __builtin_amdgcn_mfma_f32_16x16x32_bf16(af[mt], bfr[nt], acc[mt][nt], 0, 0, 0);
        __syncthreads();   // readers done before next overwrite
    }

    // epilogue: D mapping col = lane&15, row = (lane>>4)*4 + reg
    const int cn = bn + wn + fm;
    const int rm = bm + wm + (lane >> 4) * 4;
    float bv[4];
#pragma unroll
    for (int nt = 0; nt < 4; nt++) bv[nt] = bias[cn + nt * 16];
#pragma unroll
    for (int mt = 0; mt < 4; mt++) {
#pragma unroll
        for (int r = 0; r < 4; r++) {
            const size_t rowoff = (size_t)(rm + mt * 16 + r) * N;
#pragma unroll
            for (int nt = 0; nt < 4; nt++) {
                float val = acc[mt][nt][r] + bv[nt];
                if (ACT == ACT_GELU) val = 0.5f * val * (1.0f + erff(val * 0.70710678118654752f));
                if (RES) val += res[rowoff + cn + nt * 16];
                if (OUT_BF16) ((bf16*)Cout)[rowoff + cn + nt * 16] = (bf16)val;
                else          ((float*)Cout)[rowoff + cn + nt * 16] = val;
            }
        }
    }
}

// ---------------- Flash attention: one block (256 thr) per (b, h, 64-query tile)
// reads fp32 qkv, writes bf16 attn-out
__global__ __launch_bounds__(256) void fattn_kernel(const float* __restrict__ qkv,
                                                    bf16* __restrict__ out) {
    __shared__ float Qs[64][68];
    __shared__ float Ks[64][68];
    __shared__ float Vs[64][68];
    __shared__ float Ps[64][68];
    __shared__ float red[4][64];
    __shared__ float mrow[64], lrow[64], alph[64];

    const int bid = blockIdx.x;
    const int qt = bid & 15;
    const int h = (bid >> 4) & 15;
    const int b = bid >> 8;
    const int tid = threadIdx.x;
    const int ti = tid & 15, tj = tid >> 4;
    const int i0 = ti * 4, d0 = tj * 4;

    const size_t base = (size_t)b * NSEQ * (3 * DIM);
    const float* qb = qkv + base + h * HEAD_DIM;
    const float* kb = qkv + base + DIM + h * HEAD_DIM;
    const float* vb = qkv + base + 2 * DIM + h * HEAD_DIM;

    {
        const int i = tid >> 2, c = tid & 3;
        const float* src = qb + (size_t)(qt * 64 + i) * (3 * DIM) + c * 4;
#pragma unroll
        for (int f = 0; f < 4; f++) {
            float4 v4 = *(const float4*)(src + f * 16);
            const int d = f * 16 + c * 4;
            Qs[d + 0][i] = v4.x * 0.125f;
            Qs[d + 1][i] = v4.y * 0.125f;
            Qs[d + 2][i] = v4.z * 0.125f;
            Qs[d + 3][i] = v4.w * 0.125f;
        }
    }
    if (tid < 64) { mrow[tid] = -INFINITY; lrow[tid] = 0.f; }

    float o[4][4] = {};

    for (int k0 = 0; k0 < NSEQ; k0 += 64) {
        __syncthreads();
        {
            const int j = tid >> 2, c = tid & 3;
            const float* ks = kb + (size_t)(k0 + j) * (3 * DIM) + c * 4;
            const float* vs = vb + (size_t)(k0 + j) * (3 * DIM) + c * 4;
#pragma unroll
            for (int f = 0; f < 4; f++) {
                float4 v4 = *(const float4*)(ks + f * 16);
                const int d = f * 16 + c * 4;
                Ks[d + 0][j] = v4.x; Ks[d + 1][j] = v4.y;
                Ks[d + 2][j] = v4.z; Ks[d + 3][j] = v4.w;
            }
#pragma unroll
            for (int f = 0; f < 4; f++) {
                *(float4*)&Vs[j][f * 16 + c * 4] = *(const float4*)(vs + f * 16);
            }
        }
        __syncthreads();

        float s[4][4] = {};
#pragma unroll 8
        for (int d = 0; d < 64; d++) {
            const float4 a = *(const float4*)&Qs[d][i0];
            const float4 w = *(const float4*)&Ks[d][d0];
            const float aa[4] = {a.x, a.y, a.z, a.w};
            const float ww[4] = {w.x, w.y, w.z, w.w};
#pragma unroll
            for (int ii = 0; ii < 4; ii++)
#pragma unroll
                for (int jj = 0; jj < 4; jj++) s[ii][jj] += aa[ii] * ww[jj];
        }
#pragma unroll
        for (int jj = 0; jj < 4; jj++)
            *(float4*)&Ps[d0 + jj][i0] = make_float4(s[0][jj], s[1][jj], s[2][jj], s[3][jj]);
        __syncthreads();

        {
            const int r = tid & 63, c = tid >> 6;
            float pm = -INFINITY;
#pragma unroll
            for (int j = c * 16; j < c * 16 + 16; j++) pm = fmaxf(pm, Ps[j][r]);
            red[c][r] = pm;
        }
        __syncthreads();
        if (tid < 64) {
            const float mo = mrow[tid];
            float mn = fmaxf(fmaxf(red[0][tid], red[1][tid]), fmaxf(red[2][tid], red[3][tid]));
            mn = fmaxf(mn, mo);
            alph[tid] = __expf(mo - mn);
            mrow[tid] = mn;
        }
        __syncthreads();
        {
            const int r = tid & 63, c = tid >> 6;
            const float m = mrow[r];
            float ps = 0.f;
#pragma unroll
            for (int j = c * 16; j < c * 16 + 16; j++) {
                const float p = __expf(Ps[j][r] - m);
                Ps[j][r] = p;
                ps += p;
            }
            red[c][r] = ps;
        }
        __syncthreads();
        if (tid < 64)
            lrow[tid] = lrow[tid] * alph[tid] + red[0][tid] + red[1][tid] + red[2][tid] + red[3][tid];

        float al[4];
#pragma unroll
        for (int ii = 0; ii < 4; ii++) al[ii] = alph[i0 + ii];
#pragma unroll
        for (int ii = 0; ii < 4; ii++)
#pragma unroll
            for (int jj = 0; jj < 4; jj++) o[ii][jj] *= al[ii];
#pragma unroll 8
        for (int j = 0; j < 64; j++) {
            const float4 p4 = *(const float4*)&Ps[j][i0];
            const float4 v4 = *(const float4*)&Vs[j][d0];
            const float pp[4] = {p4.x, p4.y, p4.z, p4.w};
            const float vv[4] = {v4.x, v4.y, v4.z, v4.w};
#pragma unroll
            for (int ii = 0; ii < 4; ii++)
#pragma unroll
                for (int jj = 0; jj < 4; jj++) o[ii][jj] += pp[ii] * vv[jj];
        }
    }
    __syncthreads();

    {
        float linv[4];
#pragma unroll
        for (int ii = 0; ii < 4; ii++) linv[ii] = 1.0f / lrow[i0 + ii];
        const size_t tq0 = (size_t)b * NSEQ + qt * 64;
#pragma unroll
        for (int ii = 0; ii < 4; ii++) {
            bf16x4 r4 = {(bf16)(o[ii][0] * linv[ii]), (bf16)(o[ii][1] * linv[ii]),
                         (bf16)(o[ii][2] * linv[ii]), (bf16)(o[ii][3] * linv[ii])};
            *(bf16x4*)&out[(tq0 + i0 + ii) * DIM + h * HEAD_DIM + d0] = r4;
        }
    }
}

// ---------------- launch ----------------
extern "C" void kernel_launch(void* const* d_in, const int* in_sizes, int n_in,
                              void* d_out, int out_size, void* d_ws, size_t ws_size,
                              hipStream_t stream) {
    const float* x      = (const float*)d_in[0];
    const float* ln1_g  = (const float*)d_in[1];
    const float* ln1_b  = (const float*)d_in[2];
    const float* qkv_w  = (const float*)d_in[3];
    const float* qkv_b  = (const float*)d_in[4];
    const float* proj_w = (const float*)d_in[5];
    const float* proj_b = (const float*)d_in[6];
    const float* ln2_g  = (const float*)d_in[7];
    const float* ln2_b  = (const float*)d_in[8];
    const float* fc1_w  = (const float*)d_in[9];
    const float* fc1_b  = (const float*)d_in[10];
    const float* fc2_w  = (const float*)d_in[11];
    const float* fc2_b  = (const float*)d_in[12];
    float* out = (float*)d_out;

    // workspace layout (bytes): all 16B aligned
    char* p = (char*)d_ws;
    bf16*  h_bf    = (bf16*)p;                 p += (size_t)TOKENS * DIM * 2;        // 8MB
    bf16*  attn_bf = (bf16*)p;                 p += (size_t)TOKENS * DIM * 2;        // 8MB
    bf16*  ffn_bf  = (bf16*)p;                 p += (size_t)TOKENS * HIDDEN * 2;     // 32MB
    float* qkv_buf = (float*)p;                p += (size_t)TOKENS * 3 * DIM * 4;    // 48MB
    bf16*  wq_bf   = (bf16*)p;                 p += (size_t)3 * DIM * DIM * 2;       // 6MB
    bf16*  wp_bf   = (bf16*)p;                 p += (size_t)DIM * DIM * 2;           // 2MB
    bf16*  w1_bf   = (bf16*)p;                 p += (size_t)HIDDEN * DIM * 2;        // 8MB
    bf16*  w2_bf   = (bf16*)p;                 p += (size_t)DIM * HIDDEN * 2;        // 8MB

    // weight conversions (every launch; graph-capture safe)
    cvt_kernel<<<3 * DIM * DIM / 1024, 256, 0, stream>>>(qkv_w, wq_bf);
    cvt_kernel<<<DIM * DIM / 1024, 256, 0, stream>>>(proj_w, wp_bf);
    cvt_kernel<<<HIDDEN * DIM / 1024, 256, 0, stream>>>(fc1_w, w1_bf);
    cvt_kernel<<<DIM * HIDDEN / 1024, 256, 0, stream>>>(fc2_w, w2_bf);

    // 1) h = LN1(x) -> bf16
    ln_kernel<<<TOKENS, 256, 0, stream>>>(x, ln1_g, ln1_b, h_bf);
    // 2) qkv = h @ qkv_w^T + b -> fp32
    mfma_gemm<ACT_NONE, false, false><<<dim3(3 * DIM / 128, TOKENS / 128), 256, 0, stream>>>(
        h_bf, wq_bf, qkv_b, nullptr, qkv_buf, TOKENS, 3 * DIM, DIM);
    // 3) attention -> bf16
    fattn_kernel<<<BATCH * HEADS * (NSEQ / 64), 256, 0, stream>>>(qkv_buf, attn_bf);
    // 4) x1 = x + attn @ proj_w^T + b -> fp32 (d_out)
    mfma_gemm<ACT_NONE, true, false><<<dim3(DIM / 128, TOKENS / 128), 256, 0, stream>>>(
        attn_bf, wp_bf, proj_b, x, out, TOKENS, DIM, DIM);
    // 5) h2 = LN2(x1) -> bf16
    ln_kernel<<<TOKENS, 256, 0, stream>>>(out, ln2_g, ln2_b, h_bf);
    // 6) ffn = gelu(h2 @ fc1_w^T + b) -> bf16
    mfma_gemm<ACT_GELU, false, true><<<dim3(HIDDEN / 128, TOKENS / 128), 256, 0, stream>>>(
        h_bf, w1_bf, fc1_b, nullptr, ffn_bf, TOKENS, HIDDEN, DIM);
    // 7) out = x1 + ffn @ fc2_w^T + b -> fp32 (in-place residual on d_out)
    mfma_gemm<ACT_NONE, true, false><<<dim3(DIM / 128, TOKENS / 128), 256, 0, stream>>>(
        ffn_bf, w2_bf, fc2_b, out, out, TOKENS, DIM, HIDDEN);
}

// Round 4
// 423.500 us; speedup vs baseline: 13.8768x; 1.4476x over previous
//
#include <hip/hip_runtime.h>
#include <math.h>

#define DIM 1024
#define HEADS 16
#define HEAD_DIM 64
#define HIDDEN 4096
#define NSEQ 1024
#define BATCH 4
#define TOKENS (BATCH * NSEQ)
#define EPS 1e-5f

typedef __bf16 bf16;
typedef __bf16 bf16x4 __attribute__((ext_vector_type(4)));
typedef __bf16 bf16x8 __attribute__((ext_vector_type(8)));
typedef float f32x4 __attribute__((ext_vector_type(4)));

#define AS1 __attribute__((address_space(1)))
#define AS3 __attribute__((address_space(3)))

// ---------------- fp32 -> bf16 weight convert ----------------
__global__ __launch_bounds__(256) void cvt_kernel(const float* __restrict__ s,
                                                  bf16* __restrict__ d) {
    const int i = (blockIdx.x * 256 + threadIdx.x) * 4;
    const float4 v = *(const float4*)(s + i);
    bf16x4 o = {(bf16)v.x, (bf16)v.y, (bf16)v.z, (bf16)v.w};
    *(bf16x4*)(d + i) = o;
}

// ---------------- LayerNorm: one block (256 thr) per token, bf16 out ----------------
__global__ __launch_bounds__(256) void ln_kernel(const float* __restrict__ x,
                                                 const float* __restrict__ g,
                                                 const float* __restrict__ b,
                                                 bf16* __restrict__ out) {
    const int t = blockIdx.x;
    const int tid = threadIdx.x;
    const float* row = x + (size_t)t * DIM;
    float v[4];
    float s1 = 0.f, s2 = 0.f;
#pragma unroll
    for (int i = 0; i < 4; i++) {
        v[i] = row[tid + i * 256];
        s1 += v[i];
        s2 += v[i] * v[i];
    }
    __shared__ float w1[4], w2[4];
#pragma unroll
    for (int off = 32; off > 0; off >>= 1) {
        s1 += __shfl_down(s1, off, 64);
        s2 += __shfl_down(s2, off, 64);
    }
    const int wave = tid >> 6;
    if ((tid & 63) == 0) { w1[wave] = s1; w2[wave] = s2; }
    __syncthreads();
    const float sum = w1[0] + w1[1] + w1[2] + w1[3];
    const float ssq = w2[0] + w2[1] + w2[2] + w2[3];
    const float mu = sum * (1.0f / DIM);
    const float var = ssq * (1.0f / DIM) - mu * mu;
    const float rstd = rsqrtf(var + EPS);
    bf16* orow = out + (size_t)t * DIM;
#pragma unroll
    for (int i = 0; i < 4; i++) {
        const int idx = tid + i * 256;
        orow[idx] = (bf16)((v[i] - mu) * rstd * g[idx] + b[idx]);
    }
}

// ---------------- bf16 MFMA GEMM (m97 structure) ----------------
// C[M,N] = A[M,K] @ W[N,K]^T + bias (+gelu) (+res). 128x128 tile, BK=32,
// 256 thr = 4 waves, each wave a 64x64 quadrant (4x4 MFMA tiles of 16x16x32).
// VT mode: for n>=2048 (V third of QKV), write transposed vT[b][n-2048][m%1024].
#define ACT_NONE 0
#define ACT_GELU 1

template <int ACT, bool RES, bool OUT_BF16, bool VT>
__global__ __launch_bounds__(256) void mfma_gemm(const bf16* __restrict__ A,
                                                 const bf16* __restrict__ W,
                                                 const float* __restrict__ bias,
                                                 const float* __restrict__ res,
                                                 void* __restrict__ Cout,
                                                 bf16* __restrict__ vTout,
                                                 int M, int N, int K) {
    __shared__ __align__(16) bf16 As[128 * 32];
    __shared__ __align__(16) bf16 Bs[128 * 32];

    const int tid = threadIdx.x;
    const int w = tid >> 6, lane = tid & 63;
    const int bm = blockIdx.y * 128, bn = blockIdx.x * 128;

    const bf16* pa = A + (size_t)(bm + (tid >> 2)) * K + (tid & 3) * 8;
    const bf16* pb = W + (size_t)(bn + (tid >> 2)) * K + (tid & 3) * 8;
    const size_t rowskip = (size_t)64 * K;
    char* ldsA = (char*)As + (w << 10);
    char* ldsB = (char*)Bs + (w << 10);

    const int wm = (w & 1) * 64, wn = (w >> 1) * 64;
    const int fm = lane & 15, fk = (lane >> 4) * 8;
    const bf16* aoff = As + (wm + fm) * 32 + fk;
    const bf16* boff = Bs + (wn + fm) * 32 + fk;

    f32x4 acc[4][4] = {};

    for (int kk = 0; kk < K; kk += 32) {
        __builtin_amdgcn_global_load_lds((const AS1 void*)pa, (AS3 void*)ldsA, 16, 0, 0);
        __builtin_amdgcn_global_load_lds((const AS1 void*)(pa + rowskip), (AS3 void*)(ldsA + 4096), 16, 0, 0);
        __builtin_amdgcn_global_load_lds((const AS1 void*)pb, (AS3 void*)ldsB, 16, 0, 0);
        __builtin_amdgcn_global_load_lds((const AS1 void*)(pb + rowskip), (AS3 void*)(ldsB + 4096), 16, 0, 0);
        pa += 32; pb += 32;
        __syncthreads();

        bf16x8 af[4], bfr[4];
#pragma unroll
        for (int t = 0; t < 4; t++) af[t] = *(const bf16x8*)(aoff + t * 16 * 32);
#pragma unroll
        for (int t = 0; t < 4; t++) bfr[t] = *(const bf16x8*)(boff + t * 16 * 32);
#pragma unroll
        for (int mt = 0; mt < 4; mt++)
#pragma unroll
            for (int nt = 0; nt < 4; nt++)
                acc[mt][nt] = __builtin_amdgcn_mfma_f32_16x16x32_bf16(af[mt], bfr[nt], acc[mt][nt], 0, 0, 0);
        __syncthreads();
    }

    // epilogue: D mapping col = lane&15, row = (lane>>4)*4 + reg
    const int cn = bn + wn + fm;
    const int rm = bm + wm + (lane >> 4) * 4;
    float bv[4];
#pragma unroll
    for (int nt = 0; nt < 4; nt++) bv[nt] = bias[cn + nt * 16];

    if (VT && bn >= 2048) {
        // transposed store: vT[b][dg][j], 4 consecutive j per lane per (mt,nt)
        const int dg0 = cn - 2048;
#pragma unroll
        for (int mt = 0; mt < 4; mt++) {
            const int mrow = rm + mt * 16;
            const int bI = mrow >> 10, j0 = mrow & 1023;
#pragma unroll
            for (int nt = 0; nt < 4; nt++) {
                const int dg = dg0 + nt * 16;
                bf16x4 v4 = {(bf16)(acc[mt][nt][0] + bv[nt]), (bf16)(acc[mt][nt][1] + bv[nt]),
                             (bf16)(acc[mt][nt][2] + bv[nt]), (bf16)(acc[mt][nt][3] + bv[nt])};
                *(bf16x4*)(vTout + ((size_t)(bI * 1024 + dg)) * 1024 + j0) = v4;
            }
        }
        return;
    }

#pragma unroll
    for (int mt = 0; mt < 4; mt++) {
#pragma unroll
        for (int r = 0; r < 4; r++) {
            const size_t rowoff = (size_t)(rm + mt * 16 + r) * N;
#pragma unroll
            for (int nt = 0; nt < 4; nt++) {
                float val = acc[mt][nt][r] + bv[nt];
                if (ACT == ACT_GELU) val = 0.5f * val * (1.0f + erff(val * 0.70710678118654752f));
                if (RES) val += res[rowoff + cn + nt * 16];
                if (OUT_BF16) ((bf16*)Cout)[rowoff + cn + nt * 16] = (bf16)val;
                else          ((float*)Cout)[rowoff + cn + nt * 16] = val;
            }
        }
    }
}

// ---------------- MFMA flash attention ----------------
// One block (256 thr = 4 waves) per (b, h, 64-query tile). Wave w owns queries
// 16w..16w+16. K tile and V^T tile staged via global_load_lds with XOR chunk
// swizzle (chunk c stored at c^(row&7)) -> conflict-free ds_read_b128 b-frags.
// S = Q@K^T via MFMA (C-layout: row=query=(lane>>4)*4+r, col=key=lane&15+16nt);
// softmax stats in registers via 16-lane shfl_xor; P -> LDS (wave-local, pad 68)
// -> A-frags for P@V^T MFMA.
__global__ __launch_bounds__(256) void fattn_mfma(const bf16* __restrict__ qkv,
                                                  const bf16* __restrict__ vT,
                                                  bf16* __restrict__ out) {
    __shared__ __align__(16) bf16 Ks[64 * 64];
    __shared__ __align__(16) bf16 Vt[64 * 64];
    __shared__ __align__(16) bf16 Ps[64 * 68];

    const int bid = blockIdx.x;          // b*256 + h*16 + qt
    const int qt = bid & 15;
    const int h = (bid >> 4) & 15;
    const int b = bid >> 8;
    const int tid = threadIdx.x;
    const int w = tid >> 6, lane = tid & 63;
    const int li = lane & 15, g = lane >> 4;

    // Q a-frags (persistent): m = query (w*16 + li), k = d-range g*8 + 32ks
    bf16x8 aQ[2];
    {
        const size_t tok = (size_t)b * NSEQ + qt * 64 + w * 16 + li;
#pragma unroll
        for (int ks = 0; ks < 2; ks++)
            aQ[ks] = *(const bf16x8*)(qkv + tok * (3 * DIM) + h * HEAD_DIM + g * 8 + 32 * ks);
    }

    float mrun[4] = {-INFINITY, -INFINITY, -INFINITY, -INFINITY};
    float lrun[4] = {0.f, 0.f, 0.f, 0.f};
    f32x4 o[4] = {};

    // staging indices (per-lane): two shots per wave, linear chunk idx
    const int idx0 = w * 128 + lane;
    const int idx1 = idx0 + 64;
    const int jl0 = idx0 >> 3, c0 = (idx0 & 7) ^ (jl0 & 7);
    const int jl1 = idx1 >> 3, c1 = (idx1 & 7) ^ (jl1 & 7);
    bf16* ldsK0 = Ks + (size_t)(w * 128) * 8;        // +lane*16B by HW
    bf16* ldsK1 = Ks + (size_t)(w * 128 + 64) * 8;
    bf16* ldsV0 = Vt + (size_t)(w * 128) * 8;
    bf16* ldsV1 = Vt + (size_t)(w * 128 + 64) * 8;
    const bf16* kbase = qkv + (size_t)b * NSEQ * (3 * DIM) + DIM + h * HEAD_DIM;
    const bf16* vbase = vT + ((size_t)b * DIM + h * HEAD_DIM) * NSEQ;

    for (int k0 = 0; k0 < NSEQ; k0 += 64) {
        __syncthreads();  // previous iteration's readers of Ks/Vt done
        __builtin_amdgcn_global_load_lds((const AS1 void*)(kbase + (size_t)(k0 + jl0) * (3 * DIM) + c0 * 8),
                                         (AS3 void*)ldsK0, 16, 0, 0);
        __builtin_amdgcn_global_load_lds((const AS1 void*)(kbase + (size_t)(k0 + jl1) * (3 * DIM) + c1 * 8),
                                         (AS3 void*)ldsK1, 16, 0, 0);
        __builtin_amdgcn_global_load_lds((const AS1 void*)(vbase + (size_t)jl0 * NSEQ + k0 + c0 * 8),
                                         (AS3 void*)ldsV0, 16, 0, 0);
        __builtin_amdgcn_global_load_lds((const AS1 void*)(vbase + (size_t)jl1 * NSEQ + k0 + c1 * 8),
                                         (AS3 void*)ldsV1, 16, 0, 0);
        __syncthreads();  // drain vmcnt, make Ks/Vt visible

        // ---- S = Q@K^T : 4 col-tiles x 2 k-steps ----
        f32x4 s[4] = {};
#pragma unroll
        for (int ks = 0; ks < 2; ks++) {
#pragma unroll
            for (int nt = 0; nt < 4; nt++) {
                const int j = li + 16 * nt;
                const int p = (g + 4 * ks) ^ (j & 7);
                bf16x8 bK = *(const bf16x8*)(Ks + j * 64 + p * 8);
                s[nt] = __builtin_amdgcn_mfma_f32_16x16x32_bf16(aQ[ks], bK, s[nt], 0, 0, 0);
            }
        }
        // scale
#pragma unroll
        for (int nt = 0; nt < 4; nt++) s[nt] *= 0.125f;

        // ---- softmax stats in registers (rows = (g)*4+r within wave strip) ----
        float m4[4], rs[4], alpha[4];
#pragma unroll
        for (int r = 0; r < 4; r++)
            m4[r] = fmaxf(fmaxf(s[0][r], s[1][r]), fmaxf(s[2][r], s[3][r]));
#pragma unroll
        for (int mask = 1; mask < 16; mask <<= 1)
#pragma unroll
            for (int r = 0; r < 4; r++) m4[r] = fmaxf(m4[r], __shfl_xor(m4[r], mask, 64));
#pragma unroll
        for (int r = 0; r < 4; r++) {
            const float mn = fmaxf(mrun[r], m4[r]);
            alpha[r] = __expf(mrun[r] - mn);
            mrun[r] = mn;
        }
        // P = exp(S - m); write to LDS (wave-local rows)
#pragma unroll
        for (int r = 0; r < 4; r++) rs[r] = 0.f;
#pragma unroll
        for (int nt = 0; nt < 4; nt++) {
#pragma unroll
            for (int r = 0; r < 4; r++) {
                const float p = __expf(s[nt][r] - mrun[r]);
                rs[r] += p;
                Ps[(w * 16 + g * 4 + r) * 68 + li + 16 * nt] = (bf16)p;
            }
        }
#pragma unroll
        for (int mask = 1; mask < 16; mask <<= 1)
#pragma unroll
            for (int r = 0; r < 4; r++) rs[r] += __shfl_xor(rs[r], mask, 64);
#pragma unroll
        for (int r = 0; r < 4; r++) lrun[r] = lrun[r] * alpha[r] + rs[r];
        // rescale O accumulators (same C-layout rows)
#pragma unroll
        for (int nt = 0; nt < 4; nt++)
#pragma unroll
            for (int r = 0; r < 4; r++) o[nt][r] *= alpha[r];

        // ---- O += P @ V^T ----
        bf16x8 aP[2];
#pragma unroll
        for (int ks = 0; ks < 2; ks++) {
            const int off = (w * 16 + li) * 68 + g * 8 + 32 * ks;
            bf16x4 lo = *(const bf16x4*)(Ps + off);
            bf16x4 hi = *(const bf16x4*)(Ps + off + 4);
            aP[ks] = bf16x8{lo[0], lo[1], lo[2], lo[3], hi[0], hi[1], hi[2], hi[3]};
        }
#pragma unroll
        for (int ks = 0; ks < 2; ks++) {
#pragma unroll
            for (int nt = 0; nt < 4; nt++) {
                const int d = li + 16 * nt;
                const int p = (g + 4 * ks) ^ (d & 7);
                bf16x8 bV = *(const bf16x8*)(Vt + d * 64 + p * 8);
                o[nt] = __builtin_amdgcn_mfma_f32_16x16x32_bf16(aP[ks], bV, o[nt], 0, 0, 0);
            }
        }
    }

    // ---- epilogue: O /= l ----
    float linv[4];
#pragma unroll
    for (int r = 0; r < 4; r++) linv[r] = 1.0f / lrun[r];
    const size_t tok0 = (size_t)b * NSEQ + qt * 64 + w * 16 + g * 4;
#pragma unroll
    for (int r = 0; r < 4; r++) {
#pragma unroll
        for (int nt = 0; nt < 4; nt++)
            out[(tok0 + r) * DIM + h * HEAD_DIM + 16 * nt + li] = (bf16)(o[nt][r] * linv[r]);
    }
}

// ---------------- launch ----------------
extern "C" void kernel_launch(void* const* d_in, const int* in_sizes, int n_in,
                              void* d_out, int out_size, void* d_ws, size_t ws_size,
                              hipStream_t stream) {
    const float* x      = (const float*)d_in[0];
    const float* ln1_g  = (const float*)d_in[1];
    const float* ln1_b  = (const float*)d_in[2];
    const float* qkv_w  = (const float*)d_in[3];
    const float* qkv_b  = (const float*)d_in[4];
    const float* proj_w = (const float*)d_in[5];
    const float* proj_b = (const float*)d_in[6];
    const float* ln2_g  = (const float*)d_in[7];
    const float* ln2_b  = (const float*)d_in[8];
    const float* fc1_w  = (const float*)d_in[9];
    const float* fc1_b  = (const float*)d_in[10];
    const float* fc2_w  = (const float*)d_in[11];
    const float* fc2_b  = (const float*)d_in[12];
    float* out = (float*)d_out;

    char* p = (char*)d_ws;
    bf16*  h_bf    = (bf16*)p;  p += (size_t)TOKENS * DIM * 2;         // 8MB
    bf16*  attn_bf = (bf16*)p;  p += (size_t)TOKENS * DIM * 2;         // 8MB
    bf16*  ffn_bf  = (bf16*)p;  p += (size_t)TOKENS * HIDDEN * 2;      // 32MB
    bf16*  qkv_bf  = (bf16*)p;  p += (size_t)TOKENS * 3 * DIM * 2;     // 24MB
    bf16*  vT_bf   = (bf16*)p;  p += (size_t)BATCH * DIM * NSEQ * 2;   // 8MB
    bf16*  wq_bf   = (bf16*)p;  p += (size_t)3 * DIM * DIM * 2;        // 6MB
    bf16*  wp_bf   = (bf16*)p;  p += (size_t)DIM * DIM * 2;            // 2MB
    bf16*  w1_bf   = (bf16*)p;  p += (size_t)HIDDEN * DIM * 2;         // 8MB
    bf16*  w2_bf   = (bf16*)p;  p += (size_t)DIM * HIDDEN * 2;         // 8MB

    cvt_kernel<<<3 * DIM * DIM / 1024, 256, 0, stream>>>(qkv_w, wq_bf);
    cvt_kernel<<<DIM * DIM / 1024, 256, 0, stream>>>(proj_w, wp_bf);
    cvt_kernel<<<HIDDEN * DIM / 1024, 256, 0, stream>>>(fc1_w, w1_bf);
    cvt_kernel<<<DIM * HIDDEN / 1024, 256, 0, stream>>>(fc2_w, w2_bf);

    // 1) h = LN1(x) -> bf16
    ln_kernel<<<TOKENS, 256, 0, stream>>>(x, ln1_g, ln1_b, h_bf);
    // 2) qkv = h @ qkv_w^T + b -> bf16 (Q,K thirds) + transposed V -> vT_bf
    mfma_gemm<ACT_NONE, false, true, true><<<dim3(3 * DIM / 128, TOKENS / 128), 256, 0, stream>>>(
        h_bf, wq_bf, qkv_b, nullptr, qkv_bf, vT_bf, TOKENS, 3 * DIM, DIM);
    // 3) MFMA flash attention -> bf16
    fattn_mfma<<<BATCH * HEADS * (NSEQ / 64), 256, 0, stream>>>(qkv_bf, vT_bf, attn_bf);
    // 4) x1 = x + attn @ proj_w^T + b -> fp32 (d_out)
    mfma_gemm<ACT_NONE, true, false, false><<<dim3(DIM / 128, TOKENS / 128), 256, 0, stream>>>(
        attn_bf, wp_bf, proj_b, x, out, nullptr, TOKENS, DIM, DIM);
    // 5) h2 = LN2(x1) -> bf16
    ln_kernel<<<TOKENS, 256, 0, stream>>>(out, ln2_g, ln2_b, h_bf);
    // 6) ffn = gelu(h2 @ fc1_w^T + b) -> bf16
    mfma_gemm<ACT_GELU, false, true, false><<<dim3(HIDDEN / 128, TOKENS / 128), 256, 0, stream>>>(
        h_bf, w1_bf, fc1_b, nullptr, ffn_bf, nullptr, TOKENS, HIDDEN, DIM);
    // 7) out = x1 + ffn @ fc2_w^T + b -> fp32 (in-place residual on d_out)
    mfma_gemm<ACT_NONE, true, false, false><<<dim3(DIM / 128, TOKENS / 128), 256, 0, stream>>>(
        ffn_bf, w2_bf, fc2_b, out, out, nullptr, TOKENS, DIM, HIDDEN);
}

// Round 5
// 414.682 us; speedup vs baseline: 14.1719x; 1.0213x over previous
//
#include <hip/hip_runtime.h>
#include <math.h>

#define DIM 1024
#define HEADS 16
#define HEAD_DIM 64
#define HIDDEN 4096
#define NSEQ 1024
#define BATCH 4
#define TOKENS (BATCH * NSEQ)
#define EPS 1e-5f

typedef __bf16 bf16;
typedef __bf16 bf16x4 __attribute__((ext_vector_type(4)));
typedef __bf16 bf16x8 __attribute__((ext_vector_type(8)));
typedef float f32x4 __attribute__((ext_vector_type(4)));

#define AS1 __attribute__((address_space(1)))
#define AS3 __attribute__((address_space(3)))

// ---------------- fused fp32 -> bf16 weight convert (all 4 weights) ----------------
// quad-index regions: qkv_w 786432, proj_w 262144, fc1_w 1048576, fc2_w 1048576
__global__ __launch_bounds__(256) void cvt4_kernel(const float* __restrict__ s0,
                                                   const float* __restrict__ s1,
                                                   const float* __restrict__ s2,
                                                   const float* __restrict__ s3,
                                                   bf16* __restrict__ d0,
                                                   bf16* __restrict__ d1,
                                                   bf16* __restrict__ d2,
                                                   bf16* __restrict__ d3) {
    size_t q = (size_t)blockIdx.x * 256 + threadIdx.x;
    const float* s;
    bf16* d;
    if (q < 786432) { s = s0; d = d0; }
    else if (q < 786432 + 262144) { q -= 786432; s = s1; d = d1; }
    else if (q < 786432 + 262144 + 1048576) { q -= 786432 + 262144; s = s2; d = d2; }
    else { q -= 786432 + 262144 + 1048576; s = s3; d = d3; }
    const float4 v = *(const float4*)(s + q * 4);
    bf16x4 o = {(bf16)v.x, (bf16)v.y, (bf16)v.z, (bf16)v.w};
    *(bf16x4*)(d + q * 4) = o;
}

// ---------------- LayerNorm: one block (256 thr) per token, bf16 out ----------------
__global__ __launch_bounds__(256) void ln_kernel(const float* __restrict__ x,
                                                 const float* __restrict__ g,
                                                 const float* __restrict__ b,
                                                 bf16* __restrict__ out) {
    const int t = blockIdx.x;
    const int tid = threadIdx.x;
    const float* row = x + (size_t)t * DIM;
    float v[4];
    float s1 = 0.f, s2 = 0.f;
#pragma unroll
    for (int i = 0; i < 4; i++) {
        v[i] = row[tid + i * 256];
        s1 += v[i];
        s2 += v[i] * v[i];
    }
    __shared__ float w1[4], w2[4];
#pragma unroll
    for (int off = 32; off > 0; off >>= 1) {
        s1 += __shfl_down(s1, off, 64);
        s2 += __shfl_down(s2, off, 64);
    }
    const int wave = tid >> 6;
    if ((tid & 63) == 0) { w1[wave] = s1; w2[wave] = s2; }
    __syncthreads();
    const float sum = w1[0] + w1[1] + w1[2] + w1[3];
    const float ssq = w2[0] + w2[1] + w2[2] + w2[3];
    const float mu = sum * (1.0f / DIM);
    const float var = ssq * (1.0f / DIM) - mu * mu;
    const float rstd = rsqrtf(var + EPS);
    bf16* orow = out + (size_t)t * DIM;
#pragma unroll
    for (int i = 0; i < 4; i++) {
        const int idx = tid + i * 256;
        orow[idx] = (bf16)((v[i] - mu) * rstd * g[idx] + b[idx]);
    }
}

// ---------------- bf16 MFMA GEMM (m97 structure) ----------------
// C[M,N] = A[M,K] @ W[N,K]^T + bias (+gelu) (+res). 128x128 tile, BK=32,
// 256 thr = 4 waves, each wave a 64x64 quadrant (4x4 MFMA tiles of 16x16x32).
// VT: for n>=2048 (V third of QKV), write transposed vT[b][n-2048][m%1024].
// SPLITK>1: blockIdx.z = K-segment; epilogue atomicAdds fp32 partial into Cout
// (residual must be pre-loaded into Cout); bias added only by segment 0.
#define ACT_NONE 0
#define ACT_GELU 1

template <int ACT, bool RES, bool OUT_BF16, bool VT, int SPLITK>
__global__ __launch_bounds__(256) void mfma_gemm(const bf16* __restrict__ A,
                                                 const bf16* __restrict__ W,
                                                 const float* __restrict__ bias,
                                                 const float* __restrict__ res,
                                                 void* __restrict__ Cout,
                                                 bf16* __restrict__ vTout,
                                                 int M, int N, int K) {
    __shared__ __align__(16) bf16 As[128 * 32];
    __shared__ __align__(16) bf16 Bs[128 * 32];

    const int tid = threadIdx.x;
    const int w = tid >> 6, lane = tid & 63;
    const int bm = blockIdx.y * 128, bn = blockIdx.x * 128;
    const int kseg = K / SPLITK;
    const int k0 = (SPLITK > 1) ? blockIdx.z * kseg : 0;

    const bf16* pa = A + (size_t)(bm + (tid >> 2)) * K + k0 + (tid & 3) * 8;
    const bf16* pb = W + (size_t)(bn + (tid >> 2)) * K + k0 + (tid & 3) * 8;
    const size_t rowskip = (size_t)64 * K;
    char* ldsA = (char*)As + (w << 10);
    char* ldsB = (char*)Bs + (w << 10);

    const int wm = (w & 1) * 64, wn = (w >> 1) * 64;
    const int fm = lane & 15, fk = (lane >> 4) * 8;
    const bf16* aoff = As + (wm + fm) * 32 + fk;
    const bf16* boff = Bs + (wn + fm) * 32 + fk;

    f32x4 acc[4][4] = {};

    for (int kk = 0; kk < kseg; kk += 32) {
        __builtin_amdgcn_global_load_lds((const AS1 void*)pa, (AS3 void*)ldsA, 16, 0, 0);
        __builtin_amdgcn_global_load_lds((const AS1 void*)(pa + rowskip), (AS3 void*)(ldsA + 4096), 16, 0, 0);
        __builtin_amdgcn_global_load_lds((const AS1 void*)pb, (AS3 void*)ldsB, 16, 0, 0);
        __builtin_amdgcn_global_load_lds((const AS1 void*)(pb + rowskip), (AS3 void*)(ldsB + 4096), 16, 0, 0);
        pa += 32; pb += 32;
        __syncthreads();

        bf16x8 af[4], bfr[4];
#pragma unroll
        for (int t = 0; t < 4; t++) af[t] = *(const bf16x8*)(aoff + t * 16 * 32);
#pragma unroll
        for (int t = 0; t < 4; t++) bfr[t] = *(const bf16x8*)(boff + t * 16 * 32);
#pragma unroll
        for (int mt = 0; mt < 4; mt++)
#pragma unroll
            for (int nt = 0; nt < 4; nt++)
                acc[mt][nt] = __builtin_amdgcn_mfma_f32_16x16x32_bf16(af[mt], bfr[nt], acc[mt][nt], 0, 0, 0);
        __syncthreads();
    }

    // epilogue: D mapping col = lane&15, row = (lane>>4)*4 + reg
    const int cn = bn + wn + fm;
    const int rm = bm + wm + (lane >> 4) * 4;
    float bv[4];
#pragma unroll
    for (int nt = 0; nt < 4; nt++)
        bv[nt] = (SPLITK > 1 && blockIdx.z != 0) ? 0.f : bias[cn + nt * 16];

    if (SPLITK > 1) {
        float* outp = (float*)Cout;
#pragma unroll
        for (int mt = 0; mt < 4; mt++) {
#pragma unroll
            for (int r = 0; r < 4; r++) {
                const size_t rowoff = (size_t)(rm + mt * 16 + r) * N;
#pragma unroll
                for (int nt = 0; nt < 4; nt++)
                    atomicAdd(outp + rowoff + cn + nt * 16, acc[mt][nt][r] + bv[nt]);
            }
        }
        return;
    }

    if (VT && bn >= 2048) {
        const int dg0 = cn - 2048;
#pragma unroll
        for (int mt = 0; mt < 4; mt++) {
            const int mrow = rm + mt * 16;
            const int bI = mrow >> 10, j0 = mrow & 1023;
#pragma unroll
            for (int nt = 0; nt < 4; nt++) {
                const int dg = dg0 + nt * 16;
                bf16x4 v4 = {(bf16)(acc[mt][nt][0] + bv[nt]), (bf16)(acc[mt][nt][1] + bv[nt]),
                             (bf16)(acc[mt][nt][2] + bv[nt]), (bf16)(acc[mt][nt][3] + bv[nt])};
                *(bf16x4*)(vTout + ((size_t)(bI * 1024 + dg)) * 1024 + j0) = v4;
            }
        }
        return;
    }

#pragma unroll
    for (int mt = 0; mt < 4; mt++) {
#pragma unroll
        for (int r = 0; r < 4; r++) {
            const size_t rowoff = (size_t)(rm + mt * 16 + r) * N;
#pragma unroll
            for (int nt = 0; nt < 4; nt++) {
                float val = acc[mt][nt][r] + bv[nt];
                if (ACT == ACT_GELU) val = 0.5f * val * (1.0f + erff(val * 0.70710678118654752f));
                if (RES) val += res[rowoff + cn + nt * 16];
                if (OUT_BF16) ((bf16*)Cout)[rowoff + cn + nt * 16] = (bf16)val;
                else          ((float*)Cout)[rowoff + cn + nt * 16] = val;
            }
        }
    }
}

// ---------------- MFMA flash attention ----------------
__global__ __launch_bounds__(256) void fattn_mfma(const bf16* __restrict__ qkv,
                                                  const bf16* __restrict__ vT,
                                                  bf16* __restrict__ out) {
    __shared__ __align__(16) bf16 Ks[64 * 64];
    __shared__ __align__(16) bf16 Vt[64 * 64];
    __shared__ __align__(16) bf16 Ps[64 * 68];

    const int bid = blockIdx.x;
    const int qt = bid & 15;
    const int h = (bid >> 4) & 15;
    const int b = bid >> 8;
    const int tid = threadIdx.x;
    const int w = tid >> 6, lane = tid & 63;
    const int li = lane & 15, g = lane >> 4;

    bf16x8 aQ[2];
    {
        const size_t tok = (size_t)b * NSEQ + qt * 64 + w * 16 + li;
#pragma unroll
        for (int ks = 0; ks < 2; ks++)
            aQ[ks] = *(const bf16x8*)(qkv + tok * (3 * DIM) + h * HEAD_DIM + g * 8 + 32 * ks);
    }

    float mrun[4] = {-INFINITY, -INFINITY, -INFINITY, -INFINITY};
    float lrun[4] = {0.f, 0.f, 0.f, 0.f};
    f32x4 o[4] = {};

    const int idx0 = w * 128 + lane;
    const int idx1 = idx0 + 64;
    const int jl0 = idx0 >> 3, c0 = (idx0 & 7) ^ (jl0 & 7);
    const int jl1 = idx1 >> 3, c1 = (idx1 & 7) ^ (jl1 & 7);
    bf16* ldsK0 = Ks + (size_t)(w * 128) * 8;
    bf16* ldsK1 = Ks + (size_t)(w * 128 + 64) * 8;
    bf16* ldsV0 = Vt + (size_t)(w * 128) * 8;
    bf16* ldsV1 = Vt + (size_t)(w * 128 + 64) * 8;
    const bf16* kbase = qkv + (size_t)b * NSEQ * (3 * DIM) + DIM + h * HEAD_DIM;
    const bf16* vbase = vT + ((size_t)b * DIM + h * HEAD_DIM) * NSEQ;

    for (int k0 = 0; k0 < NSEQ; k0 += 64) {
        __syncthreads();
        __builtin_amdgcn_global_load_lds((const AS1 void*)(kbase + (size_t)(k0 + jl0) * (3 * DIM) + c0 * 8),
                                         (AS3 void*)ldsK0, 16, 0, 0);
        __builtin_amdgcn_global_load_lds((const AS1 void*)(kbase + (size_t)(k0 + jl1) * (3 * DIM) + c1 * 8),
                                         (AS3 void*)ldsK1, 16, 0, 0);
        __builtin_amdgcn_global_load_lds((const AS1 void*)(vbase + (size_t)jl0 * NSEQ + k0 + c0 * 8),
                                         (AS3 void*)ldsV0, 16, 0, 0);
        __builtin_amdgcn_global_load_lds((const AS1 void*)(vbase + (size_t)jl1 * NSEQ + k0 + c1 * 8),
                                         (AS3 void*)ldsV1, 16, 0, 0);
        __syncthreads();

        f32x4 s[4] = {};
#pragma unroll
        for (int ks = 0; ks < 2; ks++) {
#pragma unroll
            for (int nt = 0; nt < 4; nt++) {
                const int j = li + 16 * nt;
                const int p = (g + 4 * ks) ^ (j & 7);
                bf16x8 bK = *(const bf16x8*)(Ks + j * 64 + p * 8);
                s[nt] = __builtin_amdgcn_mfma_f32_16x16x32_bf16(aQ[ks], bK, s[nt], 0, 0, 0);
            }
        }
#pragma unroll
        for (int nt = 0; nt < 4; nt++) s[nt] *= 0.125f;

        float m4[4], rs[4], alpha[4];
#pragma unroll
        for (int r = 0; r < 4; r++)
            m4[r] = fmaxf(fmaxf(s[0][r], s[1][r]), fmaxf(s[2][r], s[3][r]));
#pragma unroll
        for (int mask = 1; mask < 16; mask <<= 1)
#pragma unroll
            for (int r = 0; r < 4; r++) m4[r] = fmaxf(m4[r], __shfl_xor(m4[r], mask, 64));
#pragma unroll
        for (int r = 0; r < 4; r++) {
            const float mn = fmaxf(mrun[r], m4[r]);
            alpha[r] = __expf(mrun[r] - mn);
            mrun[r] = mn;
        }
#pragma unroll
        for (int r = 0; r < 4; r++) rs[r] = 0.f;
#pragma unroll
        for (int nt = 0; nt < 4; nt++) {
#pragma unroll
            for (int r = 0; r < 4; r++) {
                const float p = __expf(s[nt][r] - mrun[r]);
                rs[r] += p;
                Ps[(w * 16 + g * 4 + r) * 68 + li + 16 * nt] = (bf16)p;
            }
        }
#pragma unroll
        for (int mask = 1; mask < 16; mask <<= 1)
#pragma unroll
            for (int r = 0; r < 4; r++) rs[r] += __shfl_xor(rs[r], mask, 64);
#pragma unroll
        for (int r = 0; r < 4; r++) lrun[r] = lrun[r] * alpha[r] + rs[r];
#pragma unroll
        for (int nt = 0; nt < 4; nt++)
#pragma unroll
            for (int r = 0; r < 4; r++) o[nt][r] *= alpha[r];

        bf16x8 aP[2];
#pragma unroll
        for (int ks = 0; ks < 2; ks++) {
            const int off = (w * 16 + li) * 68 + g * 8 + 32 * ks;
            bf16x4 lo = *(const bf16x4*)(Ps + off);
            bf16x4 hi = *(const bf16x4*)(Ps + off + 4);
            aP[ks] = bf16x8{lo[0], lo[1], lo[2], lo[3], hi[0], hi[1], hi[2], hi[3]};
        }
#pragma unroll
        for (int ks = 0; ks < 2; ks++) {
#pragma unroll
            for (int nt = 0; nt < 4; nt++) {
                const int d = li + 16 * nt;
                const int p = (g + 4 * ks) ^ (d & 7);
                bf16x8 bV = *(const bf16x8*)(Vt + d * 64 + p * 8);
                o[nt] = __builtin_amdgcn_mfma_f32_16x16x32_bf16(aP[ks], bV, o[nt], 0, 0, 0);
            }
        }
    }

    float linv[4];
#pragma unroll
    for (int r = 0; r < 4; r++) linv[r] = 1.0f / lrun[r];
    const size_t tok0 = (size_t)b * NSEQ + qt * 64 + w * 16 + g * 4;
#pragma unroll
    for (int r = 0; r < 4; r++) {
#pragma unroll
        for (int nt = 0; nt < 4; nt++)
            out[(tok0 + r) * DIM + h * HEAD_DIM + 16 * nt + li] = (bf16)(o[nt][r] * linv[r]);
    }
}

// ---------------- launch ----------------
extern "C" void kernel_launch(void* const* d_in, const int* in_sizes, int n_in,
                              void* d_out, int out_size, void* d_ws, size_t ws_size,
                              hipStream_t stream) {
    const float* x      = (const float*)d_in[0];
    const float* ln1_g  = (const float*)d_in[1];
    const float* ln1_b  = (const float*)d_in[2];
    const float* qkv_w  = (const float*)d_in[3];
    const float* qkv_b  = (const float*)d_in[4];
    const float* proj_w = (const float*)d_in[5];
    const float* proj_b = (const float*)d_in[6];
    const float* ln2_g  = (const float*)d_in[7];
    const float* ln2_b  = (const float*)d_in[8];
    const float* fc1_w  = (const float*)d_in[9];
    const float* fc1_b  = (const float*)d_in[10];
    const float* fc2_w  = (const float*)d_in[11];
    const float* fc2_b  = (const float*)d_in[12];
    float* out = (float*)d_out;

    char* p = (char*)d_ws;
    bf16*  h_bf    = (bf16*)p;  p += (size_t)TOKENS * DIM * 2;
    bf16*  attn_bf = (bf16*)p;  p += (size_t)TOKENS * DIM * 2;
    bf16*  ffn_bf  = (bf16*)p;  p += (size_t)TOKENS * HIDDEN * 2;
    bf16*  qkv_bf  = (bf16*)p;  p += (size_t)TOKENS * 3 * DIM * 2;
    bf16*  vT_bf   = (bf16*)p;  p += (size_t)BATCH * DIM * NSEQ * 2;
    bf16*  wq_bf   = (bf16*)p;  p += (size_t)3 * DIM * DIM * 2;
    bf16*  wp_bf   = (bf16*)p;  p += (size_t)DIM * DIM * 2;
    bf16*  w1_bf   = (bf16*)p;  p += (size_t)HIDDEN * DIM * 2;
    bf16*  w2_bf   = (bf16*)p;  p += (size_t)DIM * HIDDEN * 2;

    // fused weight convert: (3M + 1M + 4M + 4M) elems / 4 per thread / 256 per block
    cvt4_kernel<<<(3145728 + 1048576 + 4194304 + 4194304) / 1024, 256, 0, stream>>>(
        qkv_w, proj_w, fc1_w, fc2_w, wq_bf, wp_bf, w1_bf, w2_bf);

    // 1) h = LN1(x) -> bf16
    ln_kernel<<<TOKENS, 256, 0, stream>>>(x, ln1_g, ln1_b, h_bf);
    // 2) qkv = h @ qkv_w^T + b -> bf16 (Q,K) + transposed V -> vT_bf
    mfma_gemm<ACT_NONE, false, true, true, 1><<<dim3(3 * DIM / 128, TOKENS / 128), 256, 0, stream>>>(
        h_bf, wq_bf, qkv_b, nullptr, qkv_bf, vT_bf, TOKENS, 3 * DIM, DIM);
    // 3) MFMA flash attention -> bf16
    fattn_mfma<<<BATCH * HEADS * (NSEQ / 64), 256, 0, stream>>>(qkv_bf, vT_bf, attn_bf);
    // 4) out = x; then out += attn @ proj_w^T + b  (split-K 2, atomic)
    hipMemcpyAsync(out, x, (size_t)TOKENS * DIM * sizeof(float), hipMemcpyDeviceToDevice, stream);
    mfma_gemm<ACT_NONE, false, false, false, 2><<<dim3(DIM / 128, TOKENS / 128, 2), 256, 0, stream>>>(
        attn_bf, wp_bf, proj_b, nullptr, out, nullptr, TOKENS, DIM, DIM);
    // 5) h2 = LN2(x1) -> bf16
    ln_kernel<<<TOKENS, 256, 0, stream>>>(out, ln2_g, ln2_b, h_bf);
    // 6) ffn = gelu(h2 @ fc1_w^T + b) -> bf16
    mfma_gemm<ACT_GELU, false, true, false, 1><<<dim3(HIDDEN / 128, TOKENS / 128), 256, 0, stream>>>(
        h_bf, w1_bf, fc1_b, nullptr, ffn_bf, nullptr, TOKENS, HIDDEN, DIM);
    // 7) out += ffn @ fc2_w^T + b  (split-K 2, atomic; out already holds x1)
    mfma_gemm<ACT_NONE, false, false, false, 2><<<dim3(DIM / 128, TOKENS / 128, 2), 256, 0, stream>>>(
        ffn_bf, w2_bf, fc2_b, nullptr, out, nullptr, TOKENS, DIM, HIDDEN);
}